// Round 7
// baseline (354.111 us; speedup 1.0000x reference)
//
#include <hip/hip_runtime.h>

#define SEQ 2048
#define DMODEL 2048
#define NHEADS 16
#define DKH 128

typedef __bf16 bf16;
typedef __attribute__((ext_vector_type(8))) __bf16 bf16x8;
typedef __attribute__((ext_vector_type(4))) __bf16 bf16x4;
typedef __attribute__((ext_vector_type(4))) float f32x4;

#define AS1 __attribute__((address_space(1)))
#define AS3 __attribute__((address_space(3)))

__device__ __forceinline__ void async_copy16(const void* g, void* l) {
  __builtin_amdgcn_global_load_lds((AS1 void*)(unsigned long long)g,
                                   (AS3 void*)l, 16, 0, 0);
}

// XOR-swizzle for 64-wide (8-chunk) LDS rows: slot = chunk ^ (row&7)
__device__ __forceinline__ int swz(int chunk, int row) {
  return (chunk ^ (row & 7)) << 3;
}
// XOR-swizzle for 128-wide (16-chunk) LDS rows: slot = chunk ^ (row&15)
__device__ __forceinline__ int swz16(int chunk, int row) {
  return (chunk ^ (row & 15)) << 3;
}

// ---------------------------------------------------------------------------
// Generic bf16 GEMM, "BT" pattern: C[m,n] = scale * sum_k A[m,k]*B[n,k] (+bias[n])
// 128x128 tile, BK=64, 4 waves of 64x64 via 16x16x32 MFMA, swizzled LDS.
// Used for the QKV projection (z=3, 768 blocks = 3/CU).
// Known ceiling: ~784 TF / MfmaUtil 32% (m97-structure plateau; 8-phase ports
// R1-R3 landed at the same ~770 TF — structural, not schedule-fixable here).
// ---------------------------------------------------------------------------
template <typename OutT, bool BIAS>
__global__ __launch_bounds__(256) void gemm_bt(
    const bf16* __restrict__ A, const bf16* __restrict__ B,
    const float* __restrict__ bias, OutT* __restrict__ C,
    int M, int N, int K, int lda, int ldb, int ldo, float scale,
    long long sA, long long sB, long long sC, long long sBias) {
  A += (long long)blockIdx.z * sA;
  B += (long long)blockIdx.z * sB;
  C += (long long)blockIdx.z * sC;
  const float* biasp = BIAS ? (bias + (long long)blockIdx.z * sBias) : nullptr;

  const int m0 = blockIdx.y * 128;
  const int n0 = blockIdx.x * 128;

  __shared__ __align__(16) bf16 As[128 * 64];
  __shared__ __align__(16) bf16 Bs[128 * 64];

  const int tid = threadIdx.x;
  const int wave = tid >> 6;
  const int lane = tid & 63;
  const int srow = wave * 8 + (lane >> 3);
  const int scol = ((lane & 7) ^ (lane >> 3)) * 8;  // swizzled source chunk
  const int wr = (wave >> 1) * 64;
  const int wc = (wave & 1) * 64;
  const int lr = lane & 15;
  const int quad = lane >> 4;

  const bf16* ag = A + (long long)(m0 + srow) * lda + scol;
  const bf16* bg = B + (long long)(n0 + srow) * ldb + scol;

  f32x4 acc[4][4];
#pragma unroll
  for (int i = 0; i < 4; ++i)
#pragma unroll
    for (int j = 0; j < 4; ++j) {
      acc[i][j][0] = 0.f; acc[i][j][1] = 0.f;
      acc[i][j][2] = 0.f; acc[i][j][3] = 0.f;
    }

  for (int kt = 0; kt < K; kt += 64) {
#pragma unroll
    for (int i = 0; i < 4; ++i) {
      async_copy16(ag + kt + (long long)i * 32 * lda, As + (i * 32 + wave * 8) * 64);
      async_copy16(bg + kt + (long long)i * 32 * ldb, Bs + (i * 32 + wave * 8) * 64);
    }
    __syncthreads();
#pragma unroll
    for (int kk = 0; kk < 64; kk += 32) {
      bf16x8 af[4], bfr[4];
#pragma unroll
      for (int i = 0; i < 4; ++i) {
        const int ra = wr + i * 16 + lr;
        const int rb = wc + i * 16 + lr;
        af[i]  = *(const bf16x8*)(As + ra * 64 + swz((kk >> 3) + quad, ra));
        bfr[i] = *(const bf16x8*)(Bs + rb * 64 + swz((kk >> 3) + quad, rb));
      }
#pragma unroll
      for (int i = 0; i < 4; ++i)
#pragma unroll
        for (int j = 0; j < 4; ++j)
          acc[i][j] = __builtin_amdgcn_mfma_f32_16x16x32_bf16(af[i], bfr[j], acc[i][j], 0, 0, 0);
    }
    __syncthreads();
  }

#pragma unroll
  for (int j = 0; j < 4; ++j) {
    const int n = n0 + wc + j * 16 + lr;
    const float bv = BIAS ? biasp[n] : 0.f;
#pragma unroll
    for (int i = 0; i < 4; ++i) {
      const int mb = m0 + wr + i * 16 + quad * 4;
#pragma unroll
      for (int r = 0; r < 4; ++r)
        C[(long long)(mb + r) * ldo + n] = (OutT)(acc[i][j][r] * scale + bv);
    }
  }
}

// ---------------------------------------------------------------------------
// 64x128-tile "BT" GEMM: C[m,n] = sum_k A[m,k]*B[n,k] (+bias[n]).
// 4 waves of 32x64 (acc 2x4), BK=64. Used for PV (z=head, 512 blocks) and
// out-proj (grid (16,32), 512 blocks = 2/CU, K=2048, bias, fp32 direct).
// ---------------------------------------------------------------------------
template <typename OutT, bool BIAS>
__global__ __launch_bounds__(256) void gemm_bt64(
    const bf16* __restrict__ A, const bf16* __restrict__ B,
    const float* __restrict__ bias, OutT* __restrict__ C,
    int K, int lda, int ldb, int ldo, float scale,
    long long sA, long long sB, long long sC) {
  A += (long long)blockIdx.z * sA;
  B += (long long)blockIdx.z * sB;
  C += (long long)blockIdx.z * sC;

  const int m0 = blockIdx.y * 64;
  const int n0 = blockIdx.x * 128;

  __shared__ __align__(16) bf16 As[64 * 64];
  __shared__ __align__(16) bf16 Bs[128 * 64];

  const int tid = threadIdx.x;
  const int wave = tid >> 6;
  const int lane = tid & 63;
  const int srow = wave * 8 + (lane >> 3);
  const int scol = ((lane & 7) ^ (lane >> 3)) * 8;
  const int wr = (wave >> 1) * 32;
  const int wc = (wave & 1) * 64;
  const int lr = lane & 15;
  const int quad = lane >> 4;

  const bf16* ag = A + (long long)(m0 + srow) * lda + scol;
  const bf16* bg = B + (long long)(n0 + srow) * ldb + scol;

  f32x4 acc[2][4];
#pragma unroll
  for (int i = 0; i < 2; ++i)
#pragma unroll
    for (int j = 0; j < 4; ++j) {
      acc[i][j][0] = 0.f; acc[i][j][1] = 0.f;
      acc[i][j][2] = 0.f; acc[i][j][3] = 0.f;
    }

  for (int kt = 0; kt < K; kt += 64) {
#pragma unroll
    for (int i = 0; i < 2; ++i)
      async_copy16(ag + kt + (long long)i * 32 * lda, As + (i * 32 + wave * 8) * 64);
#pragma unroll
    for (int i = 0; i < 4; ++i)
      async_copy16(bg + kt + (long long)i * 32 * ldb, Bs + (i * 32 + wave * 8) * 64);
    __syncthreads();
#pragma unroll
    for (int kk = 0; kk < 64; kk += 32) {
      bf16x8 af[2], bfr[4];
#pragma unroll
      for (int i = 0; i < 2; ++i) {
        const int ra = wr + i * 16 + lr;
        af[i] = *(const bf16x8*)(As + ra * 64 + swz((kk >> 3) + quad, ra));
      }
#pragma unroll
      for (int j = 0; j < 4; ++j) {
        const int rb = wc + j * 16 + lr;
        bfr[j] = *(const bf16x8*)(Bs + rb * 64 + swz((kk >> 3) + quad, rb));
      }
#pragma unroll
      for (int i = 0; i < 2; ++i)
#pragma unroll
        for (int j = 0; j < 4; ++j)
          acc[i][j] = __builtin_amdgcn_mfma_f32_16x16x32_bf16(af[i], bfr[j], acc[i][j], 0, 0, 0);
    }
    __syncthreads();
  }

#pragma unroll
  for (int j = 0; j < 4; ++j) {
    const int n = n0 + wc + j * 16 + lr;
    const float bv = BIAS ? bias[n] : 0.f;
#pragma unroll
    for (int i = 0; i < 2; ++i) {
      const int mb = m0 + wr + i * 16 + quad * 4;
#pragma unroll
      for (int r = 0; r < 4; ++r)
        C[(long long)(mb + r) * ldo + n] = (OutT)(acc[i][j][r] * scale + bv);
    }
  }
}

// ---------------------------------------------------------------------------
// QK^T -> E = exp(score/sqrt(dk)) bf16 + per-column (over s) partial sums.
// R7 retile: A-tile 128x128 resident AND B-tile 128x128 (4 nt-iters over the
// 512 strip). Wave = 64x64 of C (acc 4x4): 16 MFMA per kk vs 8 ds_reads ->
// MFMA:read ratio 2.0 (was 1.33 with the 64-row B-tile). LDS 64KB -> 2
// blocks/CU. grid (4, 16, 16). lpart shape unchanged (32 rowblocks of 64).
// ---------------------------------------------------------------------------
__global__ __launch_bounds__(256) void qk_exp(
    const bf16* __restrict__ q, const bf16* __restrict__ k,
    bf16* __restrict__ E, float* __restrict__ lpart) {
  const int h = blockIdx.z;
  const int m0 = blockIdx.y * 128;
  const int nstrip = blockIdx.x * 512;
  const bf16* A = q + (long long)h * DKH;
  const bf16* B = k + (long long)h * DKH;
  bf16* C = E + (long long)h * SEQ * SEQ;

  __shared__ __align__(16) bf16 As[128 * 128];  // 32KB
  __shared__ __align__(16) bf16 Bs[128 * 128];  // 32KB

  const int tid = threadIdx.x;
  const int wave = tid >> 6;
  const int lane = tid & 63;
  const int wr = (wave >> 1) * 64;  // A-row half
  const int wc = (wave & 1) * 64;   // B-col half
  const int lr = lane & 15;
  const int quad = lane >> 4;
  const float scale = 0.08838834764831845f;  // 1/sqrt(128)

  // stage A-tile once (resident across all 4 B-tiles)
#pragma unroll
  for (int it = 0; it < 8; ++it) {
    const int row = wave * 32 + it * 4 + (lane >> 4);
    const int chunk = (lane & 15) ^ (row & 15);
    async_copy16(A + (long long)(m0 + row) * DMODEL + chunk * 8,
                 As + (wave * 32 + it * 4) * 128);
  }

  for (int nt = 0; nt < 4; ++nt) {
    if (nt) __syncthreads();  // protect Bs while other waves still read
#pragma unroll
    for (int it = 0; it < 8; ++it) {
      const int row = wave * 32 + it * 4 + (lane >> 4);
      const int chunk = (lane & 15) ^ (row & 15);
      async_copy16(B + (long long)(nstrip + nt * 128 + row) * DMODEL + chunk * 8,
                   Bs + (wave * 32 + it * 4) * 128);
    }
    __syncthreads();  // drains A (nt=0) and B staging

    f32x4 acc[4][4];
#pragma unroll
    for (int i = 0; i < 4; ++i)
#pragma unroll
      for (int j = 0; j < 4; ++j) {
        acc[i][j][0] = 0.f; acc[i][j][1] = 0.f;
        acc[i][j][2] = 0.f; acc[i][j][3] = 0.f;
      }

#pragma unroll
    for (int kk = 0; kk < 128; kk += 32) {
      bf16x8 af[4], bfr[4];
#pragma unroll
      for (int i = 0; i < 4; ++i) {
        const int ra = wr + i * 16 + lr;
        af[i] = *(const bf16x8*)(As + ra * 128 + swz16((kk >> 3) + quad, ra));
      }
#pragma unroll
      for (int j = 0; j < 4; ++j) {
        const int rb = wc + j * 16 + lr;
        bfr[j] = *(const bf16x8*)(Bs + rb * 128 + swz16((kk >> 3) + quad, rb));
      }
#pragma unroll
      for (int i = 0; i < 4; ++i)
#pragma unroll
        for (int j = 0; j < 4; ++j)
          acc[i][j] = __builtin_amdgcn_mfma_f32_16x16x32_bf16(af[i], bfr[j], acc[i][j], 0, 0, 0);
    }

    // epilogue: exp, store E, per-column sums (register-only)
#pragma unroll
    for (int j = 0; j < 4; ++j) {
      const int n = nstrip + nt * 128 + wc + j * 16 + lr;
      float l_loc = 0.f;
#pragma unroll
      for (int i = 0; i < 4; ++i) {
        const int mb = m0 + wr + i * 16 + quad * 4;
#pragma unroll
        for (int r = 0; r < 4; ++r) {
          bf16 ev = (bf16)__expf(acc[i][j][r] * scale);
          C[(long long)(mb + r) * SEQ + n] = ev;
          l_loc += (float)ev;  // stats from the bf16-ROUNDED value PV reads
        }
      }
      l_loc += __shfl_xor(l_loc, 16, 64);  // sum the 4 quads -> 64 rows
      l_loc += __shfl_xor(l_loc, 32, 64);
      if (quad == 0)
        lpart[((long long)h * 32 + blockIdx.y * 2 + (wave >> 1)) * SEQ + n] = l_loc;
    }
  }
}

// ---------------------------------------------------------------------------
// Fused softmax-denominator + V^T scaling (replaces sm_sum + vscale):
// block (tb, h): rv[t] = 1/sum_rb lpart, kept in LDS; then scale the head's
// 128 vt rows over this 256-col t-range. grid (8, 16), 256 threads.
// ---------------------------------------------------------------------------
__global__ __launch_bounds__(256) void sum_scale(
    const float* __restrict__ lp, bf16* __restrict__ vt) {
  __shared__ float rv[256];
  const int h = blockIdx.y;
  const int t0 = blockIdx.x * 256;
  const int tid = threadIdx.x;

  float l = 0.f;
#pragma unroll
  for (int rb = 0; rb < 32; ++rb)
    l += lp[((long long)h * 32 + rb) * SEQ + t0 + tid];
  rv[tid] = 1.f / l;
  __syncthreads();

  const int tc = (tid & 31) * 8;  // col offset within the 256-range
  const int c0 = tid >> 5;        // 0..7
#pragma unroll
  for (int cc = 0; cc < 128; cc += 8) {
    const long long row = (long long)(h * DKH + cc + c0) * SEQ + t0 + tc;
    bf16x8 v = *(const bf16x8*)(vt + row);
#pragma unroll
    for (int e = 0; e < 8; ++e) v[e] = (bf16)((float)v[e] * rv[tc + e]);
    *(bf16x8*)(vt + row) = v;
  }
}

// ---------------------------------------------------------------------------
// Fused prep: one launch, uniform 256-thread blocks, partitioned by blockIdx.x:
//  [0,12288):       cvt q/k/v fp32->bf16 (4096 blocks each, 4 elems/thread)
//  [12288,24576):   Wq/Wk/Wv transpose [2048][128] -> bf16 [128][2048] (z<48)
//  [24576,28672):   Wo transpose [2048][2048] -> bf16 Wo^T
//  [28672,28680):   bias pack
// ---------------------------------------------------------------------------
__global__ __launch_bounds__(256) void prep(
    const float* __restrict__ q, const float* __restrict__ k,
    const float* __restrict__ v,
    const float* __restrict__ Wq, const float* __restrict__ Wk,
    const float* __restrict__ Wv, const float* __restrict__ Wo,
    const float* __restrict__ bq, const float* __restrict__ bk,
    const float* __restrict__ bv,
    bf16* __restrict__ Qb, bf16* __restrict__ Wt, bf16* __restrict__ Wot,
    float* __restrict__ biasQKV) {
  __shared__ float tile[32][33];
  const long long elems = (long long)SEQ * DMODEL;
  const int id = blockIdx.x;
  const int tid = threadIdx.x;

  if (id < 12288) {  // cvt
    const float* src = (id < 4096) ? q : (id < 8192) ? k : v;
    const int t = id >> 12;
    const long long i = (long long)(id & 4095) * 1024 + tid * 4;
    const float4 vv = *(const float4*)(src + i);
    bf16x4 o;
    o[0] = (bf16)vv.x; o[1] = (bf16)vv.y; o[2] = (bf16)vv.z; o[3] = (bf16)vv.w;
    *(bf16x4*)(Qb + (long long)t * elems + i) = o;
    return;
  }
  const int tx = tid & 31, ty = tid >> 5;
  if (id < 24576) {  // Wq/Wk/Wv transpose
    const int rel = id - 12288;
    const int z = rel >> 8;             // 0..47
    const int inner = rel & 255;
    const int bx = inner & 3;           // DKH/32
    const int by = inner >> 2;          // DMODEL/32
    const int g = z >> 4, hh = z & 15;
    const float* in = (g == 0 ? Wq : (g == 1 ? Wk : Wv)) + (long long)hh * DMODEL * DKH;
    bf16* o = Wt + (long long)z * DMODEL * DKH;
    const int c0 = bx * 32, r0 = by * 32;
#pragma unroll
    for (int j = 0; j < 32; j += 8)
      tile[ty + j][tx] = in[(long long)(r0 + ty + j) * DKH + c0 + tx];
    __syncthreads();
#pragma unroll
    for (int j = 0; j < 32; j += 8)
      o[(long long)(c0 + ty + j) * DMODEL + r0 + tx] = (bf16)tile[tx][ty + j];
    return;
  }
  if (id < 28672) {  // Wo transpose
    const int rel = id - 24576;
    const int bx = rel & 63, by = rel >> 6;
    const int c0 = bx * 32, r0 = by * 32;
#pragma unroll
    for (int j = 0; j < 32; j += 8)
      tile[ty + j][tx] = Wo[(long long)(r0 + ty + j) * DMODEL + c0 + tx];
    __syncthreads();
#pragma unroll
    for (int j = 0; j < 32; j += 8)
      Wot[(long long)(c0 + ty + j) * DMODEL + r0 + tx] = (bf16)tile[tx][ty + j];
    return;
  }
  {  // bias pack
    const int i = (id - 28672) * 256 + tid;
    if (i < NHEADS * DKH) {
      biasQKV[i] = bq[i];
      biasQKV[NHEADS * DKH + i] = bk[i];
      biasQKV[2 * NHEADS * DKH + i] = bv[i];
    }
  }
}

// v -> v^T, 64x64 tiles, fully vectorized (bf16x8 load AND store, 16B/lane).
// R7: the old 32x32 version moved 2B/lane (64B segments/wave) on 16MB.
__global__ __launch_bounds__(256) void transpose_v(
    const bf16* __restrict__ in, bf16* __restrict__ out) {
  __shared__ bf16 tile[64][72];  // pad 8 to break bank alignment
  const int c0 = blockIdx.x * 64, r0 = blockIdx.y * 64;
  const int tid = threadIdx.x;
  const int row = tid >> 3;       // 0..31
  const int ch = (tid & 7) * 8;   // 8-elem chunk
#pragma unroll
  for (int p = 0; p < 2; ++p) {
    const int r = row + p * 32;
    *(bf16x8*)(&tile[r][ch]) =
        *(const bf16x8*)(in + (long long)(r0 + r) * DMODEL + c0 + ch);
  }
  __syncthreads();
#pragma unroll
  for (int p = 0; p < 2; ++p) {
    const int c = row + p * 32;  // output row (channel within tile)
    bf16x8 v;
#pragma unroll
    for (int e = 0; e < 8; ++e) v[e] = tile[ch + e][c];
    *(bf16x8*)(out + (long long)(c0 + c) * SEQ + r0 + ch) = v;
  }
}

// ---------------------------------------------------------------------------
extern "C" void kernel_launch(void* const* d_in, const int* in_sizes, int n_in,
                              void* d_out, int out_size, void* d_ws, size_t ws_size,
                              hipStream_t stream) {
  const float* query = (const float*)d_in[0];
  const float* key_  = (const float*)d_in[1];
  const float* value = (const float*)d_in[2];
  const float* Wq = (const float*)d_in[3];
  const float* bq = (const float*)d_in[4];
  const float* Wk = (const float*)d_in[5];
  const float* bk = (const float*)d_in[6];
  const float* Wv = (const float*)d_in[7];
  const float* bv = (const float*)d_in[8];
  const float* Wo = (const float*)d_in[9];
  const float* bo = (const float*)d_in[10];
  float* out = (float*)d_out;

  const long long elems = (long long)SEQ * DMODEL;  // 4M
  const long long SZB = elems * 2;                  // 8MB

  char* ws = (char*)d_ws;
  bf16* Qb = (bf16*)ws;              // 3 x SZB (dead after projection)
  bf16* Wt = (bf16*)(ws + 3 * SZB);  // 3 x SZB (dead after projection)
  bf16* scores = (bf16*)ws;          // 128MB (E = exp(score)), reuses Qb/Wt
  char* p = ws + (long long)NHEADS * SEQ * SEQ * 2;
  float* biasQKV = (float*)p; p += 32 * 1024;
  bf16* Wot   = (bf16*)p; p += SZB;
  bf16* qkv   = (bf16*)p; p += 3 * SZB;
  bf16* vt    = (bf16*)p; p += SZB;
  bf16* heads = (bf16*)p; p += SZB;
  float* lpart = (float*)p; p += (long long)NHEADS * 32 * SEQ * 4;  // 4MB
  if ((size_t)(p - ws) > ws_size) return;

  // 1) fused prep (converts + weight transposes + bias pack), one launch
  prep<<<28680, 256, 0, stream>>>(query, key_, value, Wq, Wk, Wv, Wo,
                                  bq, bk, bv, Qb, Wt, Wot, biasQKV);

  // 2) QKV projections (batched z=3), 128^2 tile kernel (768 blocks = 3/CU)
  gemm_bt<bf16, true><<<dim3(16, 16, 3), 256, 0, stream>>>(
      Qb, Wt, biasQKV, qkv, SEQ, DMODEL, DMODEL, DMODEL, DMODEL, DMODEL, 1.f,
      elems, elems, elems, (long long)DMODEL);

  // 3) v -> v^T (vectorized 64x64 tiles)
  transpose_v<<<dim3(DMODEL / 64, SEQ / 64), 256, 0, stream>>>(
      qkv + 2 * elems, vt);

  // 4) E = exp(QK^T/sqrt(dk)) + column partial sums (128x128 retile)
  qk_exp<<<dim3(4, 16, NHEADS), 256, 0, stream>>>(qkv, qkv + elems, scores, lpart);

  // 5+6) fused: r[h][t] = 1/sum, fold into v^T in place
  sum_scale<<<dim3(SEQ / 256, NHEADS), 256, 0, stream>>>(lpart, vt);

  // 7) PV: O[s, h*128+c] = sum_t E[h][s][t]*vt[h*128+c][t] (512 blocks)
  gemm_bt64<bf16, false><<<dim3(1, SEQ / 64, NHEADS), 256, 0, stream>>>(
      scores, vt, nullptr, heads, SEQ, SEQ, SEQ, DMODEL, 1.f,
      (long long)SEQ * SEQ, (long long)DKH * SEQ, (long long)DKH);

  // 8) out-proj: 64x128 tiles, grid (16,32) = 512 blocks = 2/CU, K=2048,
  //    bias in epilogue, fp32 direct
  gemm_bt64<float, true><<<dim3(DMODEL / 128, SEQ / 64, 1), 256, 0, stream>>>(
      heads, Wot, bo, out, DMODEL, DMODEL, DMODEL, DMODEL, 1.f, 0, 0, 0);
}

// Round 8
// 340.341 us; speedup vs baseline: 1.0405x; 1.0405x over previous
//
#include <hip/hip_runtime.h>

#define SEQ 2048
#define DMODEL 2048
#define NHEADS 16
#define DKH 128

typedef __bf16 bf16;
typedef __attribute__((ext_vector_type(8))) __bf16 bf16x8;
typedef __attribute__((ext_vector_type(4))) __bf16 bf16x4;
typedef __attribute__((ext_vector_type(4))) float f32x4;

#define AS1 __attribute__((address_space(1)))
#define AS3 __attribute__((address_space(3)))

__device__ __forceinline__ void async_copy16(const void* g, void* l) {
  __builtin_amdgcn_global_load_lds((AS1 void*)(unsigned long long)g,
                                   (AS3 void*)l, 16, 0, 0);
}

// XOR-swizzle for 64-wide (8-chunk) LDS rows: slot = chunk ^ (row&7)
__device__ __forceinline__ int swz(int chunk, int row) {
  return (chunk ^ (row & 7)) << 3;
}
// XOR-swizzle for 128-wide (16-chunk) LDS rows: slot = chunk ^ (row&15)
__device__ __forceinline__ int swz16(int chunk, int row) {
  return (chunk ^ (row & 15)) << 3;
}

// ---------------------------------------------------------------------------
// Generic bf16 GEMM, "BT" pattern: C[m,n] = scale * sum_k A[m,k]*B[n,k] (+bias[n])
// 128x128 tile, BK=64, 4 waves of 64x64 via 16x16x32 MFMA, swizzled LDS.
// Used for the QKV projection (z=3, 768 blocks = 3/CU).
// Known ceiling: ~784 TF / MfmaUtil 32% (m97-structure plateau; 8-phase ports
// R1-R3 landed at the same ~770 TF — structural, not schedule-fixable here).
// ---------------------------------------------------------------------------
template <typename OutT, bool BIAS>
__global__ __launch_bounds__(256) void gemm_bt(
    const bf16* __restrict__ A, const bf16* __restrict__ B,
    const float* __restrict__ bias, OutT* __restrict__ C,
    int M, int N, int K, int lda, int ldb, int ldo, float scale,
    long long sA, long long sB, long long sC, long long sBias) {
  A += (long long)blockIdx.z * sA;
  B += (long long)blockIdx.z * sB;
  C += (long long)blockIdx.z * sC;
  const float* biasp = BIAS ? (bias + (long long)blockIdx.z * sBias) : nullptr;

  const int m0 = blockIdx.y * 128;
  const int n0 = blockIdx.x * 128;

  __shared__ __align__(16) bf16 As[128 * 64];
  __shared__ __align__(16) bf16 Bs[128 * 64];

  const int tid = threadIdx.x;
  const int wave = tid >> 6;
  const int lane = tid & 63;
  const int srow = wave * 8 + (lane >> 3);
  const int scol = ((lane & 7) ^ (lane >> 3)) * 8;  // swizzled source chunk
  const int wr = (wave >> 1) * 64;
  const int wc = (wave & 1) * 64;
  const int lr = lane & 15;
  const int quad = lane >> 4;

  const bf16* ag = A + (long long)(m0 + srow) * lda + scol;
  const bf16* bg = B + (long long)(n0 + srow) * ldb + scol;

  f32x4 acc[4][4];
#pragma unroll
  for (int i = 0; i < 4; ++i)
#pragma unroll
    for (int j = 0; j < 4; ++j) {
      acc[i][j][0] = 0.f; acc[i][j][1] = 0.f;
      acc[i][j][2] = 0.f; acc[i][j][3] = 0.f;
    }

  for (int kt = 0; kt < K; kt += 64) {
#pragma unroll
    for (int i = 0; i < 4; ++i) {
      async_copy16(ag + kt + (long long)i * 32 * lda, As + (i * 32 + wave * 8) * 64);
      async_copy16(bg + kt + (long long)i * 32 * ldb, Bs + (i * 32 + wave * 8) * 64);
    }
    __syncthreads();
#pragma unroll
    for (int kk = 0; kk < 64; kk += 32) {
      bf16x8 af[4], bfr[4];
#pragma unroll
      for (int i = 0; i < 4; ++i) {
        const int ra = wr + i * 16 + lr;
        const int rb = wc + i * 16 + lr;
        af[i]  = *(const bf16x8*)(As + ra * 64 + swz((kk >> 3) + quad, ra));
        bfr[i] = *(const bf16x8*)(Bs + rb * 64 + swz((kk >> 3) + quad, rb));
      }
#pragma unroll
      for (int i = 0; i < 4; ++i)
#pragma unroll
        for (int j = 0; j < 4; ++j)
          acc[i][j] = __builtin_amdgcn_mfma_f32_16x16x32_bf16(af[i], bfr[j], acc[i][j], 0, 0, 0);
    }
    __syncthreads();
  }

#pragma unroll
  for (int j = 0; j < 4; ++j) {
    const int n = n0 + wc + j * 16 + lr;
    const float bv = BIAS ? biasp[n] : 0.f;
#pragma unroll
    for (int i = 0; i < 4; ++i) {
      const int mb = m0 + wr + i * 16 + quad * 4;
#pragma unroll
      for (int r = 0; r < 4; ++r)
        C[(long long)(mb + r) * ldo + n] = (OutT)(acc[i][j][r] * scale + bv);
    }
  }
}

// ---------------------------------------------------------------------------
// 64x128-tile "BT" GEMM: C[m,n] = sum_k A[m,k]*B[n,k] (+bias[n]).
// 4 waves of 32x64 (acc 2x4), BK=64. Used for PV (z=head, 512 blocks) and
// out-proj (grid (16,32), 512 blocks = 2/CU, K=2048, bias, fp32 direct).
// ---------------------------------------------------------------------------
template <typename OutT, bool BIAS>
__global__ __launch_bounds__(256) void gemm_bt64(
    const bf16* __restrict__ A, const bf16* __restrict__ B,
    const float* __restrict__ bias, OutT* __restrict__ C,
    int K, int lda, int ldb, int ldo, float scale,
    long long sA, long long sB, long long sC) {
  A += (long long)blockIdx.z * sA;
  B += (long long)blockIdx.z * sB;
  C += (long long)blockIdx.z * sC;

  const int m0 = blockIdx.y * 64;
  const int n0 = blockIdx.x * 128;

  __shared__ __align__(16) bf16 As[64 * 64];
  __shared__ __align__(16) bf16 Bs[128 * 64];

  const int tid = threadIdx.x;
  const int wave = tid >> 6;
  const int lane = tid & 63;
  const int srow = wave * 8 + (lane >> 3);
  const int scol = ((lane & 7) ^ (lane >> 3)) * 8;
  const int wr = (wave >> 1) * 32;
  const int wc = (wave & 1) * 64;
  const int lr = lane & 15;
  const int quad = lane >> 4;

  const bf16* ag = A + (long long)(m0 + srow) * lda + scol;
  const bf16* bg = B + (long long)(n0 + srow) * ldb + scol;

  f32x4 acc[2][4];
#pragma unroll
  for (int i = 0; i < 2; ++i)
#pragma unroll
    for (int j = 0; j < 4; ++j) {
      acc[i][j][0] = 0.f; acc[i][j][1] = 0.f;
      acc[i][j][2] = 0.f; acc[i][j][3] = 0.f;
    }

  for (int kt = 0; kt < K; kt += 64) {
#pragma unroll
    for (int i = 0; i < 2; ++i)
      async_copy16(ag + kt + (long long)i * 32 * lda, As + (i * 32 + wave * 8) * 64);
#pragma unroll
    for (int i = 0; i < 4; ++i)
      async_copy16(bg + kt + (long long)i * 32 * ldb, Bs + (i * 32 + wave * 8) * 64);
    __syncthreads();
#pragma unroll
    for (int kk = 0; kk < 64; kk += 32) {
      bf16x8 af[2], bfr[4];
#pragma unroll
      for (int i = 0; i < 2; ++i) {
        const int ra = wr + i * 16 + lr;
        af[i] = *(const bf16x8*)(As + ra * 64 + swz((kk >> 3) + quad, ra));
      }
#pragma unroll
      for (int j = 0; j < 4; ++j) {
        const int rb = wc + j * 16 + lr;
        bfr[j] = *(const bf16x8*)(Bs + rb * 64 + swz((kk >> 3) + quad, rb));
      }
#pragma unroll
      for (int i = 0; i < 2; ++i)
#pragma unroll
        for (int j = 0; j < 4; ++j)
          acc[i][j] = __builtin_amdgcn_mfma_f32_16x16x32_bf16(af[i], bfr[j], acc[i][j], 0, 0, 0);
    }
    __syncthreads();
  }

#pragma unroll
  for (int j = 0; j < 4; ++j) {
    const int n = n0 + wc + j * 16 + lr;
    const float bv = BIAS ? bias[n] : 0.f;
#pragma unroll
    for (int i = 0; i < 2; ++i) {
      const int mb = m0 + wr + i * 16 + quad * 4;
#pragma unroll
      for (int r = 0; r < 4; ++r)
        C[(long long)(mb + r) * ldo + n] = (OutT)(acc[i][j][r] * scale + bv);
    }
  }
}

// ---------------------------------------------------------------------------
// QK^T -> E = exp(score/sqrt(dk)) bf16 + per-column (over s) partial sums.
// A-tile 128x128 (32KB) resident; loop 8 B-tiles of 64 rows (16KB) over a
// 512-wide strip. LDS 48KB -> 3 blocks/CU. grid (4, 16, 16).
// (R7 retile to 128x128 B-tiles dropped occupancy to 2 blocks/CU and
//  regressed — reverted per pre-commitment.)
// ---------------------------------------------------------------------------
__global__ __launch_bounds__(256) void qk_exp(
    const bf16* __restrict__ q, const bf16* __restrict__ k,
    bf16* __restrict__ E, float* __restrict__ lpart) {
  const int h = blockIdx.z;
  const int m0 = blockIdx.y * 128;
  const int nstrip = blockIdx.x * 512;
  const bf16* A = q + (long long)h * DKH;
  const bf16* B = k + (long long)h * DKH;
  bf16* C = E + (long long)h * SEQ * SEQ;

  __shared__ __align__(16) bf16 As[128 * 128];  // 32KB
  __shared__ __align__(16) bf16 Bs[64 * 128];   // 16KB

  const int tid = threadIdx.x;
  const int wave = tid >> 6;
  const int lane = tid & 63;
  const int wr = (wave >> 1) * 64;  // A-row half
  const int wc = (wave & 1) * 32;   // B-col quarter (of 64)
  const int lr = lane & 15;
  const int quad = lane >> 4;
  const float scale = 0.08838834764831845f;  // 1/sqrt(128)

  // stage A-tile once (resident across all 8 B-tiles)
#pragma unroll
  for (int it = 0; it < 8; ++it) {
    const int row = wave * 32 + it * 4 + (lane >> 4);
    const int chunk = (lane & 15) ^ (row & 15);
    async_copy16(A + (long long)(m0 + row) * DMODEL + chunk * 8,
                 As + (wave * 32 + it * 4) * 128);
  }

  for (int nt = 0; nt < 8; ++nt) {
    if (nt) __syncthreads();  // protect Bs while other waves still read
#pragma unroll
    for (int it = 0; it < 4; ++it) {
      const int row = wave * 16 + it * 4 + (lane >> 4);
      const int chunk = (lane & 15) ^ (row & 15);
      async_copy16(B + (long long)(nstrip + nt * 64 + row) * DMODEL + chunk * 8,
                   Bs + (wave * 16 + it * 4) * 128);
    }
    __syncthreads();  // drains A (nt=0) and B staging

    f32x4 acc[4][2];
#pragma unroll
    for (int i = 0; i < 4; ++i)
#pragma unroll
      for (int j = 0; j < 2; ++j) {
        acc[i][j][0] = 0.f; acc[i][j][1] = 0.f;
        acc[i][j][2] = 0.f; acc[i][j][3] = 0.f;
      }

#pragma unroll
    for (int kk = 0; kk < 128; kk += 32) {
      bf16x8 af[4], bfr[2];
#pragma unroll
      for (int i = 0; i < 4; ++i) {
        const int ra = wr + i * 16 + lr;
        af[i] = *(const bf16x8*)(As + ra * 128 + swz16((kk >> 3) + quad, ra));
      }
#pragma unroll
      for (int j = 0; j < 2; ++j) {
        const int rb = wc + j * 16 + lr;
        bfr[j] = *(const bf16x8*)(Bs + rb * 128 + swz16((kk >> 3) + quad, rb));
      }
#pragma unroll
      for (int i = 0; i < 4; ++i)
#pragma unroll
        for (int j = 0; j < 2; ++j)
          acc[i][j] = __builtin_amdgcn_mfma_f32_16x16x32_bf16(af[i], bfr[j], acc[i][j], 0, 0, 0);
    }

    // epilogue: exp, store E, per-column sums (register-only)
#pragma unroll
    for (int j = 0; j < 2; ++j) {
      const int n = nstrip + nt * 64 + wc + j * 16 + lr;
      float l_loc = 0.f;
#pragma unroll
      for (int i = 0; i < 4; ++i) {
        const int mb = m0 + wr + i * 16 + quad * 4;
#pragma unroll
        for (int r = 0; r < 4; ++r) {
          bf16 ev = (bf16)__expf(acc[i][j][r] * scale);
          C[(long long)(mb + r) * SEQ + n] = ev;
          l_loc += (float)ev;  // stats from the bf16-ROUNDED value PV reads
        }
      }
      l_loc += __shfl_xor(l_loc, 16, 64);  // sum the 4 quads -> 64 rows
      l_loc += __shfl_xor(l_loc, 32, 64);
      if (quad == 0)
        lpart[((long long)h * 32 + blockIdx.y * 2 + (wave >> 1)) * SEQ + n] = l_loc;
    }
  }
}

// ---------------------------------------------------------------------------
// Fused softmax-denominator + V^T scaling (replaces sm_sum + vscale):
// block (tb, h): rv[t] = 1/sum_rb lpart, kept in LDS; then scale the head's
// 128 vt rows over this 256-col t-range. grid (8, 16), 256 threads.
// ---------------------------------------------------------------------------
__global__ __launch_bounds__(256) void sum_scale(
    const float* __restrict__ lp, bf16* __restrict__ vt) {
  __shared__ float rv[256];
  const int h = blockIdx.y;
  const int t0 = blockIdx.x * 256;
  const int tid = threadIdx.x;

  float l = 0.f;
#pragma unroll
  for (int rb = 0; rb < 32; ++rb)
    l += lp[((long long)h * 32 + rb) * SEQ + t0 + tid];
  rv[tid] = 1.f / l;
  __syncthreads();

  const int tc = (tid & 31) * 8;  // col offset within the 256-range
  const int c0 = tid >> 5;        // 0..7
#pragma unroll
  for (int cc = 0; cc < 128; cc += 8) {
    const long long row = (long long)(h * DKH + cc + c0) * SEQ + t0 + tc;
    bf16x8 v = *(const bf16x8*)(vt + row);
#pragma unroll
    for (int e = 0; e < 8; ++e) v[e] = (bf16)((float)v[e] * rv[tc + e]);
    *(bf16x8*)(vt + row) = v;
  }
}

// ---------------------------------------------------------------------------
// Fused prep v2: one launch, uniform 256-thread blocks, by blockIdx.x:
//  [0,12288):       cvt q/k/v fp32->bf16 (4096 blocks each, 4 elems/thread)
//  [12288,15360):   Wq/Wk/Wv transpose [2048][128] -> bf16 [128][2048],
//                   64x64 tiles, float4 loads + bf16x8 stores (z<48, 64 t/slice)
//  [15360,16384):   Wo transpose [2048][2048] -> bf16 Wo^T, 64x64 tiles
//  [16384,16392):   bias pack
// (R8: the old 32x32-fp32-tile transposes wrote 33MB of bf16 via scalar 2B
//  stores — 64B segments/wave, ~4x under-vectorized.)
// ---------------------------------------------------------------------------
__global__ __launch_bounds__(256) void prep(
    const float* __restrict__ q, const float* __restrict__ k,
    const float* __restrict__ v,
    const float* __restrict__ Wq, const float* __restrict__ Wk,
    const float* __restrict__ Wv, const float* __restrict__ Wo,
    const float* __restrict__ bq, const float* __restrict__ bk,
    const float* __restrict__ bv,
    bf16* __restrict__ Qb, bf16* __restrict__ Wt, bf16* __restrict__ Wot,
    float* __restrict__ biasQKV) {
  __shared__ bf16 t64[64][72];  // padded transpose tile
  const long long elems = (long long)SEQ * DMODEL;
  const int id = blockIdx.x;
  const int tid = threadIdx.x;

  if (id < 12288) {  // cvt
    const float* src = (id < 4096) ? q : (id < 8192) ? k : v;
    const int t = id >> 12;
    const long long i = (long long)(id & 4095) * 1024 + tid * 4;
    const float4 vv = *(const float4*)(src + i);
    bf16x4 o;
    o[0] = (bf16)vv.x; o[1] = (bf16)vv.y; o[2] = (bf16)vv.z; o[3] = (bf16)vv.w;
    *(bf16x4*)(Qb + (long long)t * elems + i) = o;
    return;
  }
  if (id < 16384) {  // transposes, 64x64 tiles
    const float* in;
    bf16* o;
    int ldin, c0, r0;
    if (id < 15360) {  // Wq/Wk/Wv: per z-slice [2048][128] -> [128][2048]
      const int rel = id - 12288;
      const int z = rel >> 6;            // 0..47
      const int inner = rel & 63;
      const int g = z >> 4, hh = z & 15;
      in = (g == 0 ? Wq : (g == 1 ? Wk : Wv)) + (long long)hh * DMODEL * DKH;
      o = Wt + (long long)z * DMODEL * DKH;
      ldin = DKH;
      c0 = (inner & 1) * 64;             // dk-tile (128/64)
      r0 = (inner >> 1) * 64;            // d-tile (2048/64)
    } else {  // Wo [2048][2048] -> Wo^T
      const int rel = id - 15360;
      in = Wo; o = Wot; ldin = DMODEL;
      c0 = (rel & 31) * 64;
      r0 = (rel >> 5) * 64;
    }
    // load: 4 threads/row, 16 fp32 each (4x float4) -> bf16 tile
    {
      const int row = tid >> 2;
      const int ch = (tid & 3) * 16;
      const float* src = in + (long long)(r0 + row) * ldin + c0 + ch;
#pragma unroll
      for (int u = 0; u < 4; ++u) {
        const float4 f = *(const float4*)(src + u * 4);
        t64[row][ch + u * 4 + 0] = (bf16)f.x;
        t64[row][ch + u * 4 + 1] = (bf16)f.y;
        t64[row][ch + u * 4 + 2] = (bf16)f.z;
        t64[row][ch + u * 4 + 3] = (bf16)f.w;
      }
    }
    __syncthreads();
    // store transposed: 4 threads/output-row, 2x bf16x8 each (16B vec stores)
    {
      const int oc = tid >> 2;
      const int och = (tid & 3) * 16;
      bf16x8 v0, v1;
#pragma unroll
      for (int e = 0; e < 8; ++e) {
        v0[e] = t64[och + e][oc];
        v1[e] = t64[och + 8 + e][oc];
      }
      bf16* dst = o + (long long)(c0 + oc) * DMODEL + r0 + och;
      *(bf16x8*)dst = v0;
      *(bf16x8*)(dst + 8) = v1;
    }
    return;
  }
  {  // bias pack
    const int i = (id - 16384) * 256 + tid;
    if (i < NHEADS * DKH) {
      biasQKV[i] = bq[i];
      biasQKV[NHEADS * DKH + i] = bk[i];
      biasQKV[2 * NHEADS * DKH + i] = bv[i];
    }
  }
}

// v -> v^T, 64x64 tiles, fully vectorized (bf16x8 load AND store, 16B/lane).
__global__ __launch_bounds__(256) void transpose_v(
    const bf16* __restrict__ in, bf16* __restrict__ out) {
  __shared__ bf16 tile[64][72];  // pad 8 to break bank alignment
  const int c0 = blockIdx.x * 64, r0 = blockIdx.y * 64;
  const int tid = threadIdx.x;
  const int row = tid >> 3;       // 0..31
  const int ch = (tid & 7) * 8;   // 8-elem chunk
#pragma unroll
  for (int p = 0; p < 2; ++p) {
    const int r = row + p * 32;
    *(bf16x8*)(&tile[r][ch]) =
        *(const bf16x8*)(in + (long long)(r0 + r) * DMODEL + c0 + ch);
  }
  __syncthreads();
#pragma unroll
  for (int p = 0; p < 2; ++p) {
    const int c = row + p * 32;  // output row (channel within tile)
    bf16x8 v;
#pragma unroll
    for (int e = 0; e < 8; ++e) v[e] = tile[ch + e][c];
    *(bf16x8*)(out + (long long)(c0 + c) * SEQ + r0 + ch) = v;
  }
}

// ---------------------------------------------------------------------------
extern "C" void kernel_launch(void* const* d_in, const int* in_sizes, int n_in,
                              void* d_out, int out_size, void* d_ws, size_t ws_size,
                              hipStream_t stream) {
  const float* query = (const float*)d_in[0];
  const float* key_  = (const float*)d_in[1];
  const float* value = (const float*)d_in[2];
  const float* Wq = (const float*)d_in[3];
  const float* bq = (const float*)d_in[4];
  const float* Wk = (const float*)d_in[5];
  const float* bk = (const float*)d_in[6];
  const float* Wv = (const float*)d_in[7];
  const float* bv = (const float*)d_in[8];
  const float* Wo = (const float*)d_in[9];
  const float* bo = (const float*)d_in[10];
  float* out = (float*)d_out;

  const long long elems = (long long)SEQ * DMODEL;  // 4M
  const long long SZB = elems * 2;                  // 8MB

  char* ws = (char*)d_ws;
  bf16* Qb = (bf16*)ws;              // 3 x SZB (dead after projection)
  bf16* Wt = (bf16*)(ws + 3 * SZB);  // 3 x SZB (dead after projection)
  bf16* scores = (bf16*)ws;          // 128MB (E = exp(score)), reuses Qb/Wt
  char* p = ws + (long long)NHEADS * SEQ * SEQ * 2;
  float* biasQKV = (float*)p; p += 32 * 1024;
  bf16* Wot   = (bf16*)p; p += SZB;
  bf16* qkv   = (bf16*)p; p += 3 * SZB;
  bf16* vt    = (bf16*)p; p += SZB;
  bf16* heads = (bf16*)p; p += SZB;
  float* lpart = (float*)p; p += (long long)NHEADS * 32 * SEQ * 4;  // 4MB
  if ((size_t)(p - ws) > ws_size) return;

  // 1) fused prep (converts + vectorized weight transposes + bias pack)
  prep<<<16392, 256, 0, stream>>>(query, key_, value, Wq, Wk, Wv, Wo,
                                  bq, bk, bv, Qb, Wt, Wot, biasQKV);

  // 2) QKV projections (batched z=3), 128^2 tile kernel (768 blocks = 3/CU)
  gemm_bt<bf16, true><<<dim3(16, 16, 3), 256, 0, stream>>>(
      Qb, Wt, biasQKV, qkv, SEQ, DMODEL, DMODEL, DMODEL, DMODEL, DMODEL, 1.f,
      elems, elems, elems, (long long)DMODEL);

  // 3) v -> v^T (vectorized 64x64 tiles)
  transpose_v<<<dim3(DMODEL / 64, SEQ / 64), 256, 0, stream>>>(
      qkv + 2 * elems, vt);

  // 4) E = exp(QK^T/sqrt(dk)) + column partial sums (A-resident strip kernel)
  qk_exp<<<dim3(4, 16, NHEADS), 256, 0, stream>>>(qkv, qkv + elems, scores, lpart);

  // 5+6) fused: r[h][t] = 1/sum, fold into v^T in place
  sum_scale<<<dim3(SEQ / 256, NHEADS), 256, 0, stream>>>(lpart, vt);

  // 7) PV: O[s, h*128+c] = sum_t E[h][s][t]*vt[h*128+c][t] (512 blocks)
  gemm_bt64<bf16, false><<<dim3(1, SEQ / 64, NHEADS), 256, 0, stream>>>(
      scores, vt, nullptr, heads, SEQ, SEQ, SEQ, DMODEL, 1.f,
      (long long)SEQ * SEQ, (long long)DKH * SEQ, (long long)DKH);

  // 8) out-proj: 64x128 tiles, grid (16,32) = 512 blocks = 2/CU, K=2048,
  //    bias in epilogue, fp32 direct
  gemm_bt64<float, true><<<dim3(DMODEL / 128, SEQ / 64, 1), 256, 0, stream>>>(
      heads, Wot, bo, out, DMODEL, DMODEL, DMODEL, DMODEL, 1.f, 0, 0, 0);
}